// Round 4
// baseline (230.244 us; speedup 1.0000x reference)
//
#include <hip/hip_runtime.h>

#define BATCH 512
#define NPART 60
#define PFEAT 20
#define SFEAT 14
#define NVTX  5
#define HID   60
#define DE    20
#define DO    24
#define NCLS  2
#define HP    64          // padded hidden stride (fp16 rows)
#define LDST  68          // LDS transpose row stride in halves: write banks = 8q + m/2 -> 2-way only (free)

#define SENDER_BLOCKS (BATCH*NPART/4)   // 7680
#define PV_BLOCKS     (BATCH*NVTX/4)    // 640

typedef _Float16 half8 __attribute__((ext_vector_type(8)));
typedef float    f32x4 __attribute__((ext_vector_type(4)));

// Compiler-order fence: DS ops from one wave complete in order at the LDS pipe;
// this only stops the compiler from reordering LDS accesses across it.
#define LDS_ORDER_FENCE() asm volatile("" ::: "memory")

// ---------------------------------------------------------------------------
// Stage A: per (b,p) layer-1 partials in fp16, rows padded to HP=64 with zeros.
// 4 waves/block, wave = one bp, lane = h.
// ---------------------------------------------------------------------------
__global__ __launch_bounds__(256) void stageA_kernel(
    const float* __restrict__ x, const float* __restrict__ fr_w1,
    const float* __restrict__ fr_b1, const float* __restrict__ pv_w1,
    _Float16* __restrict__ frA, _Float16* __restrict__ frB, _Float16* __restrict__ pvA)
{
    int bp = blockIdx.x*4 + (threadIdx.x >> 6);
    int h  = threadIdx.x & 63;
    int b = bp / NPART;
    int p = bp - b * NPART;
    if (h >= HID) {
        frA[bp*HP + h] = (_Float16)0.f;
        frB[bp*HP + h] = (_Float16)0.f;
        pvA[bp*HP + h] = (_Float16)0.f;
        return;
    }
    float xr[PFEAT];
#pragma unroll
    for (int f = 0; f < PFEAT; ++f) xr[f] = x[(b*PFEAT + f)*NPART + p];

    float a = fr_b1[h], s = 0.f, c = 0.f;
#pragma unroll
    for (int f = 0; f < PFEAT; ++f) {
        float xv = xr[f];
        a += xv * fr_w1[f*HID + h];
        s += xv * fr_w1[(PFEAT + f)*HID + h];
        c += xv * pv_w1[f*HID + h];
    }
    frA[bp*HP + h] = (_Float16)a;
    frB[bp*HP + h] = (_Float16)s;
    pvA[bp*HP + h] = (_Float16)c;
}

// ---------------------------------------------------------------------------
// Stage A2: per (b,v): pvV[b,v,:] = yt[b,v] @ pv_w1[20:34] + pv_b1 (fp16, padded)
// 4 waves/block, wave = one b.
// ---------------------------------------------------------------------------
__global__ __launch_bounds__(256) void stageA2_kernel(
    const float* __restrict__ y, const float* __restrict__ pv_w1,
    const float* __restrict__ pv_b1, _Float16* __restrict__ pvV)
{
    int b = blockIdx.x*4 + (threadIdx.x >> 6);
    int h = threadIdx.x & 63;
#pragma unroll
    for (int v = 0; v < NVTX; ++v) {
        if (h >= HID) { pvV[(b*NVTX + v)*HP + h] = (_Float16)0.f; continue; }
        float acc = pv_b1[h];
#pragma unroll
        for (int f = 0; f < SFEAT; ++f)
            acc += y[(b*SFEAT + f)*NVTX + v] * pv_w1[(PFEAT + f)*HID + h];
        pvV[(b*NVTX + v)*HP + h] = (_Float16)acc;
    }
}

// ---------------------------------------------------------------------------
// Pack kernel: all MFMA B-fragment weight tables in fp16.
// B-frag (16x16x32): lane L holds B[k = kk*32 + (L>>4)*8 + j][n = u*16 + (L&15)]
// layout: Wp[((u*2 + kk)*64 + L)*8 + j]
// ---------------------------------------------------------------------------
__global__ __launch_bounds__(256) void pack_kernel(
    const float* __restrict__ fr_w2, const float* __restrict__ fr_w3,
    const float* __restrict__ pv_w2, const float* __restrict__ pv_w3,
    const float* __restrict__ fo_w1, const float* __restrict__ fo_w2,
    const float* __restrict__ fo_w3,
    _Float16* __restrict__ frW2p, _Float16* __restrict__ frW3p,
    _Float16* __restrict__ pvW2p, _Float16* __restrict__ pvW3p,
    _Float16* __restrict__ foW1p, _Float16* __restrict__ foW2p,
    _Float16* __restrict__ foW3p)
{
    for (int idx = threadIdx.x; idx < 4096; idx += 256) {   // 64x64: u<4
        int j  = idx & 7;
        int L  = (idx >> 3) & 63;
        int kk = (idx >> 9) & 1;
        int u  = idx >> 10;
        int k  = kk*32 + (L >> 4)*8 + j;
        int n  = u*16 + (L & 15);
        bool ok = (k < HID && n < HID);
        frW2p[idx] = (_Float16)(ok ? fr_w2[k*HID + n] : 0.f);
        pvW2p[idx] = (_Float16)(ok ? pv_w2[k*HID + n] : 0.f);
        foW1p[idx] = (_Float16)(ok ? fo_w1[k*HID + n] : 0.f);
        foW2p[idx] = (_Float16)(ok ? fo_w2[k*HID + n] : 0.f);
    }
    for (int idx = threadIdx.x; idx < 2048; idx += 256) {   // 64x32: u<2
        int j  = idx & 7;
        int L  = (idx >> 3) & 63;
        int kk = (idx >> 9) & 1;
        int u  = idx >> 10;
        int k  = kk*32 + (L >> 4)*8 + j;
        int n  = u*16 + (L & 15);
        frW3p[idx] = (_Float16)((k < HID && n < DE) ? fr_w3[k*DE + n] : 0.f);
        pvW3p[idx] = (_Float16)((k < HID && n < DE) ? pv_w3[k*DE + n] : 0.f);
        foW3p[idx] = (_Float16)((k < HID && n < DO) ? fo_w3[k*DO + n] : 0.f);
    }
}

// ---------------------------------------------------------------------------
// Merged edge MLP (layers 2+3) via MFMA. 4 waves/block, one group per wave,
// per-wave private LDS slice (no __syncthreads).
// Blocks [0, SENDER_BLOCKS): fr edges, g=(b,r), 59 rows, epilogue sums -> Epp
// Blocks [SENDER_BLOCKS, +PV_BLOCKS): pv edges, g=(b,v), 60 rows -> Epv2 fp16
// A-frag (16x16x32): lane L holds A[m = 16t + (L&15)][k = kk*32 + (L>>4)*8 + j]
// C-frag: lane L holds C[row = (L>>4)*4 + i][col = L&15] per 16x16 tile.
// ---------------------------------------------------------------------------
__global__ __launch_bounds__(256) void edge_mfma_kernel(
    const _Float16* __restrict__ frA, const _Float16* __restrict__ frB,
    const _Float16* __restrict__ pvV, const _Float16* __restrict__ pvA,
    const half8* __restrict__ frw2p, const half8* __restrict__ frw3p,
    const half8* __restrict__ pvw2p, const half8* __restrict__ pvw3p,
    const float* __restrict__ fr_b2, const float* __restrict__ fr_b3,
    const float* __restrict__ pv_b2, const float* __restrict__ pv_b3,
    float* __restrict__ Epp, _Float16* __restrict__ Epv2)
{
    __shared__ _Float16 lds_all[4*64*LDST];

    int wave = threadIdx.x >> 6;
    int lane = threadIdx.x & 63;
    int m    = lane & 15;
    int q    = lane >> 4;
    _Float16* lds_h2 = lds_all + wave*64*LDST;

    bool sender = blockIdx.x < SENDER_BLOCKS;

    int g, b, rv, VALID;
    const _Float16 *uni, *var;
    const half8 *w2p, *w3p;
    const float *b2, *b3;
    if (sender) {
        g = blockIdx.x*4 + wave;
        b = g / NPART; rv = g - b*NPART; VALID = NPART - 1;
        uni = frA + (size_t)g*HP; var = frB + (size_t)b*NPART*HP;
        w2p = frw2p; w3p = frw3p; b2 = fr_b2; b3 = fr_b3;
    } else {
        g = (blockIdx.x - SENDER_BLOCKS)*4 + wave;
        b = g / NVTX; rv = g - b*NVTX; VALID = NPART;
        uni = pvV + (size_t)g*HP; var = pvA + (size_t)b*NPART*HP;
        w2p = pvw2p; w3p = pvw3p; b2 = pv_b2; b3 = pv_b3;
    }

    int srcRow[4];
#pragma unroll
    for (int t = 0; t < 4; ++t) {
        int row = 16*t + m;
        int s;
        if (sender) s = (row < VALID) ? (row + (row >= rv)) : 0;
        else        s = (row < VALID) ? row : 0;
        srcRow[t] = s;
    }

    // ---- build layer-2 A fragments: h1 = relu(uni + var[srcRow]) ----
    half8 bA[4][2];
#pragma unroll
    for (int t = 0; t < 4; ++t) {
#pragma unroll
        for (int kk = 0; kk < 2; ++kk) {
            half8 u8 = *(const half8*)(uni + kk*32 + q*8);
            half8 v8 = *(const half8*)(var + (size_t)srcRow[t]*HP + kk*32 + q*8);
            half8 s8 = u8 + v8;
#pragma unroll
            for (int j = 0; j < 8; ++j) {
                _Float16 vj = s8[j];
                s8[j] = (vj > (_Float16)0.f) ? vj : (_Float16)0.f;
            }
            bA[t][kk] = s8;
        }
    }

    // ---- layer 2 MFMA: [64 x 64] @ [64 x 64] ----
    f32x4 zero4 = {0.f, 0.f, 0.f, 0.f};
    f32x4 acc2[4][4];
#pragma unroll
    for (int t = 0; t < 4; ++t)
#pragma unroll
        for (int u = 0; u < 4; ++u) acc2[t][u] = zero4;

#pragma unroll
    for (int u = 0; u < 4; ++u) {
        half8 w0 = w2p[(u*2 + 0)*64 + lane];
        half8 w1 = w2p[(u*2 + 1)*64 + lane];
#pragma unroll
        for (int t = 0; t < 4; ++t) {
            acc2[t][u] = __builtin_amdgcn_mfma_f32_16x16x32_f16(bA[t][0], w0, acc2[t][u], 0, 0, 0);
            acc2[t][u] = __builtin_amdgcn_mfma_f32_16x16x32_f16(bA[t][1], w1, acc2[t][u], 0, 0, 0);
        }
    }

    // ---- h2 = relu(acc2 + b2) -> per-wave LDS slice (C-layout -> A-layout) ----
    float rb2[4];
#pragma unroll
    for (int u = 0; u < 4; ++u) {
        int col = u*16 + m;
        rb2[u] = (col < HID) ? b2[col] : 0.f;
    }
#pragma unroll
    for (int t = 0; t < 4; ++t)
#pragma unroll
        for (int u = 0; u < 4; ++u)
#pragma unroll
            for (int i = 0; i < 4; ++i) {
                float v = acc2[t][u][i] + rb2[u];
                v = fmaxf(v, 0.f);
                lds_h2[(16*t + 4*q + i)*LDST + u*16 + m] = (_Float16)v;
            }
    LDS_ORDER_FENCE();   // same-wave DS ops are FIFO; fence only pins compiler order

    // ---- layer 3 MFMA: [64 x 64] @ [64 x 32] ----
    half8 a3[4][2];
#pragma unroll
    for (int t = 0; t < 4; ++t)
#pragma unroll
        for (int kk = 0; kk < 2; ++kk)
            a3[t][kk] = *(const half8*)(lds_h2 + (16*t + m)*LDST + kk*32 + q*8);

    f32x4 acc3[4][2];
#pragma unroll
    for (int t = 0; t < 4; ++t)
#pragma unroll
        for (int u = 0; u < 2; ++u) acc3[t][u] = zero4;

#pragma unroll
    for (int u = 0; u < 2; ++u) {
        half8 w0 = w3p[(u*2 + 0)*64 + lane];
        half8 w1 = w3p[(u*2 + 1)*64 + lane];
#pragma unroll
        for (int t = 0; t < 4; ++t) {
            acc3[t][u] = __builtin_amdgcn_mfma_f32_16x16x32_f16(a3[t][0], w0, acc3[t][u], 0, 0, 0);
            acc3[t][u] = __builtin_amdgcn_mfma_f32_16x16x32_f16(a3[t][1], w1, acc3[t][u], 0, 0, 0);
        }
    }

    // ---- epilogue: e = relu(acc3 + b3), zero invalid rows ----
    float rb3[2];
#pragma unroll
    for (int u = 0; u < 2; ++u) {
        int col = u*16 + m;
        rb3[u] = (col < DE) ? b3[col] : 0.f;
    }

    if (sender) {
#pragma unroll
        for (int u = 0; u < 2; ++u) {
            float ps = 0.f;
#pragma unroll
            for (int t = 0; t < 4; ++t)
#pragma unroll
                for (int i = 0; i < 4; ++i) {
                    int row = 16*t + 4*q + i;
                    float v = acc3[t][u][i] + rb3[u];
                    v = fmaxf(v, 0.f);
                    if (row >= VALID) v = 0.f;
                    ps += v;
                }
            ps += __shfl_xor(ps, 16);
            ps += __shfl_xor(ps, 32);
            int col = u*16 + m;
            if (q == 0 && col < DE)
                Epp[(size_t)g*DE + col] = ps;
        }
    } else {
#pragma unroll
        for (int u = 0; u < 2; ++u) {
            int col = u*16 + m;
#pragma unroll
            for (int t = 0; t < 4; ++t)
#pragma unroll
                for (int i = 0; i < 4; ++i) {
                    int row = 16*t + 4*q + i;
                    float v = acc3[t][u][i] + rb3[u];
                    v = fmaxf(v, 0.f);
                    if (row < VALID && col < DE)
                        Epv2[((size_t)g*64 + row)*DE + col] = (_Float16)v;
                }
        }
    }
}

// ---------------------------------------------------------------------------
// Prep: gather cin[b*NPART+p][64] = fp16 [ x(20) | Epp(20) | sum_v Epv(20) | 0 ]
// ---------------------------------------------------------------------------
__global__ __launch_bounds__(256) void prep_kernel(
    const float* __restrict__ x, const float* __restrict__ Epp,
    const _Float16* __restrict__ Epv2, _Float16* __restrict__ cin)
{
    int idx = blockIdx.x*256 + threadIdx.x;   // BATCH*NPART*64 total
    int bp = idx >> 6;
    int k  = idx & 63;
    int b  = bp / NPART;
    int p  = bp - b*NPART;

    float v;
    if (k < PFEAT) {
        v = x[(b*PFEAT + k)*NPART + p];
    } else if (k < PFEAT + DE) {
        v = Epp[(size_t)bp*DE + (k - PFEAT)];
    } else if (k < PFEAT + 2*DE) {
        int c = k - PFEAT - DE;
        float s = 0.f;
#pragma unroll
        for (int vv = 0; vv < NVTX; ++vv)
            s += (float)Epv2[(((size_t)b*NVTX + vv)*64 + p)*DE + c];
        v = s;
    } else {
        v = 0.f;
    }
    cin[(size_t)bp*HP + k] = (_Float16)v;
}

// ---------------------------------------------------------------------------
// Stage D via MFMA: object MLP (60->60->60->24) + particle sum + fc head.
// 4 waves/block, one batch item per wave, per-wave LDS slice.
// ---------------------------------------------------------------------------
__global__ __launch_bounds__(256) void stageD_mfma_kernel(
    const _Float16* __restrict__ cin,
    const half8* __restrict__ w1p, const half8* __restrict__ w2p,
    const half8* __restrict__ w3p,
    const float* __restrict__ b1, const float* __restrict__ b2,
    const float* __restrict__ b3,
    const float* __restrict__ fcw, const float* __restrict__ fcb,
    float* __restrict__ out)
{
    __shared__ _Float16 lds_all[4*64*LDST];

    int wave = threadIdx.x >> 6;
    int lane = threadIdx.x & 63;
    int m    = lane & 15;
    int q    = lane >> 4;
    _Float16* lds_t = lds_all + wave*64*LDST;

    int b = blockIdx.x*4 + wave;

    int srcRow[4];
#pragma unroll
    for (int t = 0; t < 4; ++t) {
        int row = 16*t + m;
        srcRow[t] = (row < NPART) ? row : 0;
    }

    const _Float16* base = cin + (size_t)b * NPART * HP;

    half8 a1[4][2];
#pragma unroll
    for (int t = 0; t < 4; ++t)
#pragma unroll
        for (int kk = 0; kk < 2; ++kk)
            a1[t][kk] = *(const half8*)(base + (size_t)srcRow[t]*HP + kk*32 + q*8);

    f32x4 zero4 = {0.f, 0.f, 0.f, 0.f};

    // ---- layer 1 MFMA ----
    f32x4 acc[4][4];
#pragma unroll
    for (int t = 0; t < 4; ++t)
#pragma unroll
        for (int u = 0; u < 4; ++u) acc[t][u] = zero4;
#pragma unroll
    for (int u = 0; u < 4; ++u) {
        half8 w0 = w1p[(u*2 + 0)*64 + lane];
        half8 w1 = w1p[(u*2 + 1)*64 + lane];
#pragma unroll
        for (int t = 0; t < 4; ++t) {
            acc[t][u] = __builtin_amdgcn_mfma_f32_16x16x32_f16(a1[t][0], w0, acc[t][u], 0, 0, 0);
            acc[t][u] = __builtin_amdgcn_mfma_f32_16x16x32_f16(a1[t][1], w1, acc[t][u], 0, 0, 0);
        }
    }

    // ---- h1 -> LDS transpose ----
    float rb1[4];
#pragma unroll
    for (int u = 0; u < 4; ++u) {
        int col = u*16 + m;
        rb1[u] = (col < HID) ? b1[col] : 0.f;
    }
#pragma unroll
    for (int t = 0; t < 4; ++t)
#pragma unroll
        for (int u = 0; u < 4; ++u)
#pragma unroll
            for (int i = 0; i < 4; ++i) {
                float v = acc[t][u][i] + rb1[u];
                lds_t[(16*t + 4*q + i)*LDST + u*16 + m] = (_Float16)fmaxf(v, 0.f);
            }
    LDS_ORDER_FENCE();

    half8 a2[4][2];
#pragma unroll
    for (int t = 0; t < 4; ++t)
#pragma unroll
        for (int kk = 0; kk < 2; ++kk)
            a2[t][kk] = *(const half8*)(lds_t + (16*t + m)*LDST + kk*32 + q*8);
    LDS_ORDER_FENCE();

    // ---- layer 2 MFMA ----
#pragma unroll
    for (int t = 0; t < 4; ++t)
#pragma unroll
        for (int u = 0; u < 4; ++u) acc[t][u] = zero4;
#pragma unroll
    for (int u = 0; u < 4; ++u) {
        half8 w0 = w2p[(u*2 + 0)*64 + lane];
        half8 w1 = w2p[(u*2 + 1)*64 + lane];
#pragma unroll
        for (int t = 0; t < 4; ++t) {
            acc[t][u] = __builtin_amdgcn_mfma_f32_16x16x32_f16(a2[t][0], w0, acc[t][u], 0, 0, 0);
            acc[t][u] = __builtin_amdgcn_mfma_f32_16x16x32_f16(a2[t][1], w1, acc[t][u], 0, 0, 0);
        }
    }

    // ---- h2 -> LDS transpose ----
    float rb2[4];
#pragma unroll
    for (int u = 0; u < 4; ++u) {
        int col = u*16 + m;
        rb2[u] = (col < HID) ? b2[col] : 0.f;
    }
#pragma unroll
    for (int t = 0; t < 4; ++t)
#pragma unroll
        for (int u = 0; u < 4; ++u)
#pragma unroll
            for (int i = 0; i < 4; ++i) {
                float v = acc[t][u][i] + rb2[u];
                lds_t[(16*t + 4*q + i)*LDST + u*16 + m] = (_Float16)fmaxf(v, 0.f);
            }
    LDS_ORDER_FENCE();

    half8 a3[4][2];
#pragma unroll
    for (int t = 0; t < 4; ++t)
#pragma unroll
        for (int kk = 0; kk < 2; ++kk)
            a3[t][kk] = *(const half8*)(lds_t + (16*t + m)*LDST + kk*32 + q*8);

    // ---- layer 3 MFMA (cols 0..31, DO=24) ----
    f32x4 acc3[4][2];
#pragma unroll
    for (int t = 0; t < 4; ++t)
#pragma unroll
        for (int u = 0; u < 2; ++u) acc3[t][u] = zero4;
#pragma unroll
    for (int u = 0; u < 2; ++u) {
        half8 w0 = w3p[(u*2 + 0)*64 + lane];
        half8 w1 = w3p[(u*2 + 1)*64 + lane];
#pragma unroll
        for (int t = 0; t < 4; ++t) {
            acc3[t][u] = __builtin_amdgcn_mfma_f32_16x16x32_f16(a3[t][0], w0, acc3[t][u], 0, 0, 0);
            acc3[t][u] = __builtin_amdgcn_mfma_f32_16x16x32_f16(a3[t][1], w1, acc3[t][u], 0, 0, 0);
        }
    }

    // ---- epilogue: relu(+b3), sum valid rows, fc head ----
    float rb3[2];
#pragma unroll
    for (int u = 0; u < 2; ++u) {
        int col = u*16 + m;
        rb3[u] = (col < DO) ? b3[col] : 0.f;
    }
    float ps[2];
#pragma unroll
    for (int u = 0; u < 2; ++u) {
        float s = 0.f;
#pragma unroll
        for (int t = 0; t < 4; ++t)
#pragma unroll
            for (int i = 0; i < 4; ++i) {
                int row = 16*t + 4*q + i;
                float v = fmaxf(acc3[t][u][i] + rb3[u], 0.f);
                if (row < NPART) s += v;
            }
        s += __shfl_xor(s, 16);
        s += __shfl_xor(s, 32);
        ps[u] = s;     // column sum for col = u*16+m, replicated over q
    }

    float part[NCLS];
#pragma unroll
    for (int c = 0; c < NCLS; ++c) {
        float pc = 0.f;
        if (m < DO)      pc += ps[0] * fcw[m*NCLS + c];
        if (16 + m < DO) pc += ps[1] * fcw[(16 + m)*NCLS + c];
        pc += __shfl_xor(pc, 1);
        pc += __shfl_xor(pc, 2);
        pc += __shfl_xor(pc, 4);
        pc += __shfl_xor(pc, 8);
        part[c] = pc;
    }
    if (lane == 0) {
        out[b*NCLS + 0] = part[0] + fcb[0];
        out[b*NCLS + 1] = part[1] + fcb[1];
    }
}

// ---------------------------------------------------------------------------
extern "C" void kernel_launch(void* const* d_in, const int* in_sizes, int n_in,
                              void* d_out, int out_size, void* d_ws, size_t ws_size,
                              hipStream_t stream)
{
    const float* x     = (const float*)d_in[0];
    const float* y     = (const float*)d_in[1];
    const float* fr_w1 = (const float*)d_in[2];
    const float* fr_b1 = (const float*)d_in[3];
    const float* fr_w2 = (const float*)d_in[4];
    const float* fr_b2 = (const float*)d_in[5];
    const float* fr_w3 = (const float*)d_in[6];
    const float* fr_b3 = (const float*)d_in[7];
    const float* pv_w1 = (const float*)d_in[8];
    const float* pv_b1 = (const float*)d_in[9];
    const float* pv_w2 = (const float*)d_in[10];
    const float* pv_b2 = (const float*)d_in[11];
    const float* pv_w3 = (const float*)d_in[12];
    const float* pv_b3 = (const float*)d_in[13];
    const float* fo_w1 = (const float*)d_in[14];
    const float* fo_b1 = (const float*)d_in[15];
    const float* fo_w2 = (const float*)d_in[16];
    const float* fo_b2 = (const float*)d_in[17];
    const float* fo_w3 = (const float*)d_in[18];
    const float* fo_b3 = (const float*)d_in[19];
    const float* fc_w  = (const float*)d_in[20];
    const float* fc_b  = (const float*)d_in[21];
    float* out = (float*)d_out;

    char* wsb = (char*)d_ws;
    size_t off = 0;
    auto alloc = [&](size_t bytes) { char* p = wsb + off; off += (bytes + 255) & ~(size_t)255; return p; };

    _Float16* frA  = (_Float16*)alloc((size_t)BATCH*NPART*HP*2);        // 3.93 MB
    _Float16* frB  = (_Float16*)alloc((size_t)BATCH*NPART*HP*2);        // 3.93 MB
    _Float16* pvA  = (_Float16*)alloc((size_t)BATCH*NPART*HP*2);        // 3.93 MB
    _Float16* pvV  = (_Float16*)alloc((size_t)BATCH*NVTX*HP*2);         // 0.33 MB
    float*    Epp  = (float*)   alloc((size_t)BATCH*NPART*DE*4);        // 2.46 MB
    _Float16* Epv2 = (_Float16*)alloc((size_t)BATCH*NVTX*64*DE*2);      // 6.55 MB
    _Float16* cin  = (_Float16*)alloc((size_t)BATCH*NPART*HP*2);        // 3.93 MB
    _Float16* frW2p = (_Float16*)alloc(4096*2);
    _Float16* frW3p = (_Float16*)alloc(2048*2);
    _Float16* pvW2p = (_Float16*)alloc(4096*2);
    _Float16* pvW3p = (_Float16*)alloc(2048*2);
    _Float16* foW1p = (_Float16*)alloc(4096*2);
    _Float16* foW2p = (_Float16*)alloc(4096*2);
    _Float16* foW3p = (_Float16*)alloc(2048*2);

    pack_kernel<<<1, 256, 0, stream>>>(fr_w2, fr_w3, pv_w2, pv_w3, fo_w1, fo_w2, fo_w3,
                                       frW2p, frW3p, pvW2p, pvW3p, foW1p, foW2p, foW3p);
    stageA_kernel<<<BATCH*NPART/4, 256, 0, stream>>>(x, fr_w1, fr_b1, pv_w1, frA, frB, pvA);
    stageA2_kernel<<<BATCH/4, 256, 0, stream>>>(y, pv_w1, pv_b1, pvV);

    edge_mfma_kernel<<<SENDER_BLOCKS + PV_BLOCKS, 256, 0, stream>>>(
        frA, frB, pvV, pvA,
        (const half8*)frW2p, (const half8*)frW3p,
        (const half8*)pvW2p, (const half8*)pvW3p,
        fr_b2, fr_b3, pv_b2, pv_b3, Epp, Epv2);

    prep_kernel<<<(BATCH*NPART*HP)/256, 256, 0, stream>>>(x, Epp, Epv2, cin);

    stageD_mfma_kernel<<<BATCH/4, 256, 0, stream>>>(cin,
        (const half8*)foW1p, (const half8*)foW2p, (const half8*)foW3p,
        fo_b1, fo_b2, fo_b3, fc_w, fc_b, out);
}

// Round 7
// 211.973 us; speedup vs baseline: 1.0862x; 1.0862x over previous
//
#include <hip/hip_runtime.h>

#define BATCH 512
#define NPART 60
#define PFEAT 20
#define SFEAT 14
#define NVTX  5
#define HID   60
#define DE    20
#define DO    24
#define NCLS  2
#define HP    64          // padded hidden stride (fp16 rows)

#define SENDER_BLOCKS (BATCH*NPART/4)    // 7680
#define PV_BLOCKS     (BATCH*NVTX/4)     // 640
#define PREA_BLOCKS   (BATCH*NPART/256)  // 120 (64 rows/wave, 4 waves/block)
#define A2_BLOCKS     (BATCH/4)          // 128

typedef _Float16 half8  __attribute__((ext_vector_type(8)));
typedef _Float16 half4v __attribute__((ext_vector_type(4)));
typedef __fp16   fp16x2 __attribute__((ext_vector_type(2)));
typedef float    f32x4  __attribute__((ext_vector_type(4)));

__device__ __forceinline__ half4v pkcvt4(f32x4 a) {
    fp16x2 lo = __builtin_amdgcn_cvt_pkrtz(a[0], a[1]);
    fp16x2 hi = __builtin_amdgcn_cvt_pkrtz(a[2], a[3]);
    half4v r;
    r[0] = (_Float16)lo[0]; r[1] = (_Float16)lo[1];
    r[2] = (_Float16)hi[0]; r[3] = (_Float16)hi[1];
    return r;
}
__device__ __forceinline__ half4v relu4(half4v a) {
#pragma unroll
    for (int j = 0; j < 4; ++j)
        a[j] = (a[j] > (_Float16)0.f) ? a[j] : (_Float16)0.f;
    return a;
}
// In-register C-layout -> A-layout transform (with relu) via identity-B MFMA:
// C-layout regs reinterpreted as 16x16x16 A-op == tile^T; one mfma vs identity
// re-transposes; result (C-layout) reinterpreted as A-op == original tile in
// A-layout. Second cvt is exact (values are f16-representable).
__device__ __forceinline__ half4v ctile_to_afrag(f32x4 acc, half4v idB) {
    half4v at = relu4(pkcvt4(acc));
    f32x4 z = {0.f, 0.f, 0.f, 0.f};
    f32x4 tD = __builtin_amdgcn_mfma_f32_16x16x16f16(at, idB, z, 0, 0, 0);
    return pkcvt4(tD);
}
__device__ __forceinline__ half4v make_idB(int m, int q) {
    half4v idB;
#pragma unroll
    for (int j = 0; j < 4; ++j)
        idB[j] = (_Float16)((q*4 + j) == m ? 1.f : 0.f);
    return idB;
}

// ---------------------------------------------------------------------------
// Pack kernel (separate launch — MUST complete before consumers; blocks of one
// launch have no ordering guarantee, G16).
// B-frag x32 (16x16x32): lane L holds B[k = kk*32 + (L>>4)*8 + j][n = u*16 + (L&15)]
// B-frag x16 (16x16x16): lane L holds B[k = kt*16 + (L>>4)*4 + j][n = u*16 + (L&15)]
// ---------------------------------------------------------------------------
__global__ __launch_bounds__(256) void pack_kernel(
    const float* __restrict__ fr_w1, const float* __restrict__ pv_w1,
    const float* __restrict__ fr_w2, const float* __restrict__ fr_w3,
    const float* __restrict__ pv_w2, const float* __restrict__ pv_w3,
    const float* __restrict__ fo_w1, const float* __restrict__ fo_w2,
    const float* __restrict__ fo_w3,
    _Float16* __restrict__ aWr,  _Float16* __restrict__ aWs,  _Float16* __restrict__ aWp,
    _Float16* __restrict__ frW2p, _Float16* __restrict__ frW3p16,
    _Float16* __restrict__ pvW2p, _Float16* __restrict__ pvW3p16,
    _Float16* __restrict__ foW1p, _Float16* __restrict__ foW2p16,
    _Float16* __restrict__ foW3p16)
{
    for (int idx = threadIdx.x; idx < 4096; idx += 256) {   // x32, u<4, kk<2
        int j  = idx & 7;
        int L  = (idx >> 3) & 63;
        int kk = (idx >> 9) & 1;
        int u  = idx >> 10;
        int k  = kk*32 + (L >> 4)*8 + j;
        int n  = u*16 + (L & 15);
        bool ok = (k < HID && n < HID);
        frW2p[idx] = (_Float16)(ok ? fr_w2[k*HID + n] : 0.f);
        pvW2p[idx] = (_Float16)(ok ? pv_w2[k*HID + n] : 0.f);
        foW1p[idx] = (_Float16)(ok ? fo_w1[k*HID + n] : 0.f);
    }
    for (int idx = threadIdx.x; idx < 2048; idx += 256) {   // x32 single-kk (stage A), u<4
        int j = idx & 7;
        int L = (idx >> 3) & 63;
        int u = idx >> 9;
        int k = (L >> 4)*8 + j;            // K=32, k<20 real
        int n = u*16 + (L & 15);
        bool ok = (k < PFEAT && n < HID);
        aWr[idx] = (_Float16)(ok ? fr_w1[k*HID + n] : 0.f);
        aWs[idx] = (_Float16)(ok ? fr_w1[(PFEAT + k)*HID + n] : 0.f);
        aWp[idx] = (_Float16)(ok ? pv_w1[k*HID + n] : 0.f);
    }
    for (int idx = threadIdx.x; idx < 4096; idx += 256) {   // x16, u<4: fo_w2
        int j  = idx & 3;
        int L  = (idx >> 2) & 63;
        int kt = (idx >> 8) & 3;
        int u  = idx >> 10;
        int k  = kt*16 + (L >> 4)*4 + j;
        int n  = u*16 + (L & 15);
        foW2p16[idx] = (_Float16)((k < HID && n < HID) ? fo_w2[k*HID + n] : 0.f);
    }
    for (int idx = threadIdx.x; idx < 2048; idx += 256) {   // x16, u<2: w3 tables
        int j  = idx & 3;
        int L  = (idx >> 2) & 63;
        int kt = (idx >> 8) & 3;
        int u  = idx >> 10;
        int k  = kt*16 + (L >> 4)*4 + j;
        int n  = u*16 + (L & 15);
        frW3p16[idx] = (_Float16)((k < HID && n < DE) ? fr_w3[k*DE + n] : 0.f);
        pvW3p16[idx] = (_Float16)((k < HID && n < DE) ? pv_w3[k*DE + n] : 0.f);
        foW3p16[idx] = (_Float16)((k < HID && n < DO) ? fo_w3[k*DO + n] : 0.f);
    }
}

// ---------------------------------------------------------------------------
// Fused pre-kernel: two independent block ranges (no intra-launch deps).
//  [0, PREA_BLOCKS): MFMA stage A — frA/frB/pvA layer-1 partials, 64 bp-rows/wave
//  [PREA_BLOCKS, +A2_BLOCKS): stage A2 — pvV (vertex layer-1 part + bias)
// ---------------------------------------------------------------------------
__global__ __launch_bounds__(256) void fused_pre_kernel(
    const float* __restrict__ x, const float* __restrict__ y,
    const float* __restrict__ fr_b1,
    const float* __restrict__ pv_w1, const float* __restrict__ pv_b1,
    const half8* __restrict__ aWr, const half8* __restrict__ aWs,
    const half8* __restrict__ aWp,
    _Float16* __restrict__ frA, _Float16* __restrict__ frB,
    _Float16* __restrict__ pvA, _Float16* __restrict__ pvV)
{
    int wave = threadIdx.x >> 6;
    int lane = threadIdx.x & 63;
    int m    = lane & 15;
    int q    = lane >> 4;

    if (blockIdx.x < PREA_BLOCKS) {
        // ---- MFMA stage A: rows = 64 consecutive bp, cols = 3 x 64 (frA|frB|pvA)
        int wv = blockIdx.x*4 + wave;          // 0..479
        int rowBase = wv*64;
        half8 aA[4];
#pragma unroll
        for (int t = 0; t < 4; ++t) {
            int bp = rowBase + 16*t + m;
            int b = bp / NPART;
            int p = bp - b*NPART;
            const float* xb = x + (size_t)b*PFEAT*NPART + p;
            half8 v8;
#pragma unroll
            for (int j = 0; j < 8; ++j) {
                int k = q*8 + j;
                float xv = (k < PFEAT) ? xb[(size_t)k*NPART] : 0.f;
                v8[j] = (_Float16)xv;
            }
            aA[t] = v8;
        }
#pragma unroll
        for (int mat = 0; mat < 3; ++mat) {
            const half8* Wt = (mat == 0) ? aWr : (mat == 1) ? aWs : aWp;
            _Float16*    Ot = (mat == 0) ? frA : (mat == 1) ? frB : pvA;
            f32x4 acc[4][4];
#pragma unroll
            for (int u = 0; u < 4; ++u) {
                int col = u*16 + m;
                float bv = (mat == 0 && col < HID) ? fr_b1[col] : 0.f;
                f32x4 bi = {bv, bv, bv, bv};
#pragma unroll
                for (int t = 0; t < 4; ++t) acc[t][u] = bi;
            }
#pragma unroll
            for (int u = 0; u < 4; ++u) {
                half8 w = Wt[u*64 + lane];
#pragma unroll
                for (int t = 0; t < 4; ++t)
                    acc[t][u] = __builtin_amdgcn_mfma_f32_16x16x32_f16(aA[t], w, acc[t][u], 0, 0, 0);
            }
#pragma unroll
            for (int t = 0; t < 4; ++t)
#pragma unroll
                for (int u = 0; u < 4; ++u)
#pragma unroll
                    for (int i = 0; i < 4; ++i)
                        Ot[(size_t)(rowBase + 16*t + 4*q + i)*HP + u*16 + m] = (_Float16)acc[t][u][i];
        }
    } else {
        // ---- stage A2: pvV[b,v,:] = yt[b,v] @ pv_w1[20:34] + pv_b1
        int b = (blockIdx.x - PREA_BLOCKS)*4 + wave;
        int h = lane;
#pragma unroll
        for (int v = 0; v < NVTX; ++v) {
            if (h >= HID) { pvV[(b*NVTX + v)*HP + h] = (_Float16)0.f; continue; }
            float acc = pv_b1[h];
#pragma unroll
            for (int f = 0; f < SFEAT; ++f)
                acc += y[(b*SFEAT + f)*NVTX + v] * pv_w1[(PFEAT + f)*HID + h];
            pvV[(b*NVTX + v)*HP + h] = (_Float16)acc;
        }
    }
}

// ---------------------------------------------------------------------------
// Merged edge MLP (layers 2+3), MFMA only, ZERO LDS. 4 waves/block, 1 group/wave.
// Blocks [0, SENDER_BLOCKS): fr edges, g=(b,r), 59 rows, row-sum -> Epp (f32)
// Blocks [SENDER_BLOCKS, +PV_BLOCKS): pv edges, g=(b,v), 60 rows -> Epv2 (f16)
// Layer 2: 16x16x32 (bias in C-init); transpose via identity-MFMA; layer 3:
// 16x16x16 (bias in C-init).
// ---------------------------------------------------------------------------
__global__ __launch_bounds__(256) void edge_mfma_kernel(
    const _Float16* __restrict__ frA, const _Float16* __restrict__ frB,
    const _Float16* __restrict__ pvV, const _Float16* __restrict__ pvA,
    const half8*  __restrict__ frw2p, const half4v* __restrict__ frw3p16,
    const half8*  __restrict__ pvw2p, const half4v* __restrict__ pvw3p16,
    const float* __restrict__ fr_b2, const float* __restrict__ fr_b3,
    const float* __restrict__ pv_b2, const float* __restrict__ pv_b3,
    float* __restrict__ Epp, _Float16* __restrict__ Epv2)
{
    int wave = threadIdx.x >> 6;
    int lane = threadIdx.x & 63;
    int m    = lane & 15;
    int q    = lane >> 4;
    half4v idB = make_idB(m, q);

    bool sender = blockIdx.x < SENDER_BLOCKS;

    int g, b, rv, VALID;
    const _Float16 *uni, *var;
    const half8  *w2p;
    const half4v *w3p;
    const float *b2, *b3;
    if (sender) {
        g = blockIdx.x*4 + wave;
        b = g / NPART; rv = g - b*NPART; VALID = NPART - 1;
        uni = frA + (size_t)g*HP; var = frB + (size_t)b*NPART*HP;
        w2p = frw2p; w3p = frw3p16; b2 = fr_b2; b3 = fr_b3;
    } else {
        g = (blockIdx.x - SENDER_BLOCKS)*4 + wave;
        b = g / NVTX; rv = g - b*NVTX; VALID = NPART;
        uni = pvV + (size_t)g*HP; var = pvA + (size_t)b*NPART*HP;
        w2p = pvw2p; w3p = pvw3p16; b2 = pv_b2; b3 = pv_b3;
    }

    int srcRow[4];
#pragma unroll
    for (int t = 0; t < 4; ++t) {
        int row = 16*t + m;
        int s;
        if (sender) s = (row < VALID) ? (row + (row >= rv)) : 0;
        else        s = (row < VALID) ? row : 0;
        srcRow[t] = s;
    }

    // ---- layer-2 A fragments: h1 = relu(uni + var[srcRow]) ----
    half8 bA[4][2];
#pragma unroll
    for (int t = 0; t < 4; ++t) {
#pragma unroll
        for (int kk = 0; kk < 2; ++kk) {
            half8 u8 = *(const half8*)(uni + kk*32 + q*8);
            half8 v8 = *(const half8*)(var + (size_t)srcRow[t]*HP + kk*32 + q*8);
            half8 s8 = u8 + v8;
#pragma unroll
            for (int j = 0; j < 8; ++j) {
                _Float16 vj = s8[j];
                s8[j] = (vj > (_Float16)0.f) ? vj : (_Float16)0.f;
            }
            bA[t][kk] = s8;
        }
    }

    // ---- layer 2 MFMA, bias in C-init ----
    f32x4 acc2[4][4];
#pragma unroll
    for (int u = 0; u < 4; ++u) {
        int col = u*16 + m;
        float bv = (col < HID) ? b2[col] : 0.f;
        f32x4 bi = {bv, bv, bv, bv};
#pragma unroll
        for (int t = 0; t < 4; ++t) acc2[t][u] = bi;
    }
#pragma unroll
    for (int u = 0; u < 4; ++u) {
        half8 w0 = w2p[(u*2 + 0)*64 + lane];
        half8 w1 = w2p[(u*2 + 1)*64 + lane];
#pragma unroll
        for (int t = 0; t < 4; ++t) {
            acc2[t][u] = __builtin_amdgcn_mfma_f32_16x16x32_f16(bA[t][0], w0, acc2[t][u], 0, 0, 0);
            acc2[t][u] = __builtin_amdgcn_mfma_f32_16x16x32_f16(bA[t][1], w1, acc2[t][u], 0, 0, 0);
        }
    }

    // ---- in-register transpose: h2 (relu'd) -> A-layout frags ----
    half4v a3[4][4];
#pragma unroll
    for (int t = 0; t < 4; ++t)
#pragma unroll
        for (int u = 0; u < 4; ++u)
            a3[t][u] = ctile_to_afrag(acc2[t][u], idB);

    // ---- layer 3 MFMA (16x16x16), bias in C-init ----
    f32x4 acc3[4][2];
#pragma unroll
    for (int u = 0; u < 2; ++u) {
        int col = u*16 + m;
        float bv = (col < DE) ? b3[col] : 0.f;
        f32x4 bi = {bv, bv, bv, bv};
#pragma unroll
        for (int t = 0; t < 4; ++t) acc3[t][u] = bi;
    }
#pragma unroll
    for (int u = 0; u < 2; ++u)
#pragma unroll
        for (int kt = 0; kt < 4; ++kt) {
            half4v w = w3p[(u*4 + kt)*64 + lane];
#pragma unroll
            for (int t = 0; t < 4; ++t)
                acc3[t][u] = __builtin_amdgcn_mfma_f32_16x16x16f16(a3[t][kt], w, acc3[t][u], 0, 0, 0);
        }

    // ---- epilogue: e = relu(acc3), zero invalid rows ----
    if (sender) {
#pragma unroll
        for (int u = 0; u < 2; ++u) {
            float ps = 0.f;
#pragma unroll
            for (int t = 0; t < 4; ++t)
#pragma unroll
                for (int i = 0; i < 4; ++i) {
                    int row = 16*t + 4*q + i;
                    float v = fmaxf(acc3[t][u][i], 0.f);
                    if (row >= VALID) v = 0.f;
                    ps += v;
                }
            ps += __shfl_xor(ps, 16);
            ps += __shfl_xor(ps, 32);
            int col = u*16 + m;
            if (q == 0 && col < DE)
                Epp[(size_t)g*DE + col] = ps;
        }
    } else {
#pragma unroll
        for (int u = 0; u < 2; ++u) {
            int col = u*16 + m;
#pragma unroll
            for (int t = 0; t < 4; ++t)
#pragma unroll
                for (int i = 0; i < 4; ++i) {
                    int row = 16*t + 4*q + i;
                    float v = fmaxf(acc3[t][u][i], 0.f);
                    if (row < VALID && col < DE)
                        Epv2[((size_t)g*64 + row)*DE + col] = (_Float16)v;
                }
        }
    }
}

// ---------------------------------------------------------------------------
// Prep: gather cin[b*NPART+p][64] = fp16 [ x(20) | Epp(20) | sum_v Epv(20) | 0 ]
// ---------------------------------------------------------------------------
__global__ __launch_bounds__(256) void prep_kernel(
    const float* __restrict__ x, const float* __restrict__ Epp,
    const _Float16* __restrict__ Epv2, _Float16* __restrict__ cin)
{
    int idx = blockIdx.x*256 + threadIdx.x;   // BATCH*NPART*64 total
    int bp = idx >> 6;
    int k  = idx & 63;
    int b  = bp / NPART;
    int p  = bp - b*NPART;

    float v;
    if (k < PFEAT) {
        v = x[(b*PFEAT + k)*NPART + p];
    } else if (k < PFEAT + DE) {
        v = Epp[(size_t)bp*DE + (k - PFEAT)];
    } else if (k < PFEAT + 2*DE) {
        int c = k - PFEAT - DE;
        float s = 0.f;
#pragma unroll
        for (int vv = 0; vv < NVTX; ++vv)
            s += (float)Epv2[(((size_t)b*NVTX + vv)*64 + p)*DE + c];
        v = s;
    } else {
        v = 0.f;
    }
    cin[(size_t)bp*HP + k] = (_Float16)v;
}

// ---------------------------------------------------------------------------
// Stage D: object MLP (60->60->60->24) + particle sum + fc head. MFMA, no LDS.
// 4 waves/block, one batch item per wave.
// ---------------------------------------------------------------------------
__global__ __launch_bounds__(256) void stageD_mfma_kernel(
    const _Float16* __restrict__ cin,
    const half8*  __restrict__ w1p, const half4v* __restrict__ w2p16,
    const half4v* __restrict__ w3p16,
    const float* __restrict__ b1, const float* __restrict__ b2,
    const float* __restrict__ b3,
    const float* __restrict__ fcw, const float* __restrict__ fcb,
    float* __restrict__ out)
{
    int wave = threadIdx.x >> 6;
    int lane = threadIdx.x & 63;
    int m    = lane & 15;
    int q    = lane >> 4;
    half4v idB = make_idB(m, q);

    int b = blockIdx.x*4 + wave;

    int srcRow[4];
#pragma unroll
    for (int t = 0; t < 4; ++t) {
        int row = 16*t + m;
        srcRow[t] = (row < NPART) ? row : 0;
    }

    const _Float16* base = cin + (size_t)b * NPART * HP;

    half8 a1[4][2];
#pragma unroll
    for (int t = 0; t < 4; ++t)
#pragma unroll
        for (int kk = 0; kk < 2; ++kk)
            a1[t][kk] = *(const half8*)(base + (size_t)srcRow[t]*HP + kk*32 + q*8);

    // ---- layer 1 MFMA (16x16x32), bias in C-init ----
    f32x4 acc[4][4];
#pragma unroll
    for (int u = 0; u < 4; ++u) {
        int col = u*16 + m;
        float bv = (col < HID) ? b1[col] : 0.f;
        f32x4 bi = {bv, bv, bv, bv};
#pragma unroll
        for (int t = 0; t < 4; ++t) acc[t][u] = bi;
    }
#pragma unroll
    for (int u = 0; u < 4; ++u) {
        half8 w0 = w1p[(u*2 + 0)*64 + lane];
        half8 w1 = w1p[(u*2 + 1)*64 + lane];
#pragma unroll
        for (int t = 0; t < 4; ++t) {
            acc[t][u] = __builtin_amdgcn_mfma_f32_16x16x32_f16(a1[t][0], w0, acc[t][u], 0, 0, 0);
            acc[t][u] = __builtin_amdgcn_mfma_f32_16x16x32_f16(a1[t][1], w1, acc[t][u], 0, 0, 0);
        }
    }

    // ---- transpose h1 -> A frags ----
    half4v a2[4][4];
#pragma unroll
    for (int t = 0; t < 4; ++t)
#pragma unroll
        for (int u = 0; u < 4; ++u)
            a2[t][u] = ctile_to_afrag(acc[t][u], idB);

    // ---- layer 2 MFMA (16x16x16), bias in C-init ----
    f32x4 acc2[4][4];
#pragma unroll
    for (int u = 0; u < 4; ++u) {
        int col = u*16 + m;
        float bv = (col < HID) ? b2[col] : 0.f;
        f32x4 bi = {bv, bv, bv, bv};
#pragma unroll
        for (int t = 0; t < 4; ++t) acc2[t][u] = bi;
    }
#pragma unroll
    for (int u = 0; u < 4; ++u)
#pragma unroll
        for (int kt = 0; kt < 4; ++kt) {
            half4v w = w2p16[(u*4 + kt)*64 + lane];
#pragma unroll
            for (int t = 0; t < 4; ++t)
                acc2[t][u] = __builtin_amdgcn_mfma_f32_16x16x16f16(a2[t][kt], w, acc2[t][u], 0, 0, 0);
        }

    // ---- transpose h2 -> A frags ----
    half4v a3[4][4];
#pragma unroll
    for (int t = 0; t < 4; ++t)
#pragma unroll
        for (int u = 0; u < 4; ++u)
            a3[t][u] = ctile_to_afrag(acc2[t][u], idB);

    // ---- layer 3 MFMA (16x16x16), bias in C-init ----
    f32x4 acc3[4][2];
#pragma unroll
    for (int u = 0; u < 2; ++u) {
        int col = u*16 + m;
        float bv = (col < DO) ? b3[col] : 0.f;
        f32x4 bi = {bv, bv, bv, bv};
#pragma unroll
        for (int t = 0; t < 4; ++t) acc3[t][u] = bi;
    }
#pragma unroll
    for (int u = 0; u < 2; ++u)
#pragma unroll
        for (int kt = 0; kt < 4; ++kt) {
            half4v w = w3p16[(u*4 + kt)*64 + lane];
#pragma unroll
            for (int t = 0; t < 4; ++t)
                acc3[t][u] = __builtin_amdgcn_mfma_f32_16x16x16f16(a3[t][kt], w, acc3[t][u], 0, 0, 0);
        }

    // ---- epilogue: relu, sum valid rows, fc head ----
    float ps[2];
#pragma unroll
    for (int u = 0; u < 2; ++u) {
        float s = 0.f;
#pragma unroll
        for (int t = 0; t < 4; ++t)
#pragma unroll
            for (int i = 0; i < 4; ++i) {
                int row = 16*t + 4*q + i;
                float v = fmaxf(acc3[t][u][i], 0.f);
                if (row < NPART) s += v;
            }
        s += __shfl_xor(s, 16);
        s += __shfl_xor(s, 32);
        ps[u] = s;     // column sum for col = u*16+m, replicated over q
    }

    float part[NCLS];
#pragma unroll
    for (int c = 0; c < NCLS; ++c) {
        float pc = 0.f;
        if (m < DO)      pc += ps[0] * fcw[m*NCLS + c];
        if (16 + m < DO) pc += ps[1] * fcw[(16 + m)*NCLS + c];
        pc += __shfl_xor(pc, 1);
        pc += __shfl_xor(pc, 2);
        pc += __shfl_xor(pc, 4);
        pc += __shfl_xor(pc, 8);
        part[c] = pc;
    }
    if (lane == 0) {
        out[b*NCLS + 0] = part[0] + fcb[0];
        out[b*NCLS + 1] = part[1] + fcb[1];
    }
}

// ---------------------------------------------------------------------------
extern "C" void kernel_launch(void* const* d_in, const int* in_sizes, int n_in,
                              void* d_out, int out_size, void* d_ws, size_t ws_size,
                              hipStream_t stream)
{
    const float* x     = (const float*)d_in[0];
    const float* y     = (const float*)d_in[1];
    const float* fr_w1 = (const float*)d_in[2];
    const float* fr_b1 = (const float*)d_in[3];
    const float* fr_w2 = (const float*)d_in[4];
    const float* fr_b2 = (const float*)d_in[5];
    const float* fr_w3 = (const float*)d_in[6];
    const float* fr_b3 = (const float*)d_in[7];
    const float* pv_w1 = (const float*)d_in[8];
    const float* pv_b1 = (const float*)d_in[9];
    const float* pv_w2 = (const float*)d_in[10];
    const float* pv_b2 = (const float*)d_in[11];
    const float* pv_w3 = (const float*)d_in[12];
    const float* pv_b3 = (const float*)d_in[13];
    const float* fo_w1 = (const float*)d_in[14];
    const float* fo_b1 = (const float*)d_in[15];
    const float* fo_w2 = (const float*)d_in[16];
    const float* fo_b2 = (const float*)d_in[17];
    const float* fo_w3 = (const float*)d_in[18];
    const float* fo_b3 = (const float*)d_in[19];
    const float* fc_w  = (const float*)d_in[20];
    const float* fc_b  = (const float*)d_in[21];
    float* out = (float*)d_out;

    char* wsb = (char*)d_ws;
    size_t off = 0;
    auto alloc = [&](size_t bytes) { char* p = wsb + off; off += (bytes + 255) & ~(size_t)255; return p; };

    _Float16* frA  = (_Float16*)alloc((size_t)BATCH*NPART*HP*2);        // 3.93 MB
    _Float16* frB  = (_Float16*)alloc((size_t)BATCH*NPART*HP*2);        // 3.93 MB
    _Float16* pvA  = (_Float16*)alloc((size_t)BATCH*NPART*HP*2);        // 3.93 MB
    _Float16* pvV  = (_Float16*)alloc((size_t)BATCH*NVTX*HP*2);         // 0.33 MB
    float*    Epp  = (float*)   alloc((size_t)BATCH*NPART*DE*4);        // 2.46 MB
    _Float16* Epv2 = (_Float16*)alloc((size_t)BATCH*NVTX*64*DE*2);      // 6.55 MB
    _Float16* cin  = (_Float16*)alloc((size_t)BATCH*NPART*HP*2);        // 3.93 MB
    _Float16* aWr     = (_Float16*)alloc(2048*2);
    _Float16* aWs     = (_Float16*)alloc(2048*2);
    _Float16* aWp     = (_Float16*)alloc(2048*2);
    _Float16* frW2p   = (_Float16*)alloc(4096*2);
    _Float16* frW3p16 = (_Float16*)alloc(2048*2);
    _Float16* pvW2p   = (_Float16*)alloc(4096*2);
    _Float16* pvW3p16 = (_Float16*)alloc(2048*2);
    _Float16* foW1p   = (_Float16*)alloc(4096*2);
    _Float16* foW2p16 = (_Float16*)alloc(4096*2);
    _Float16* foW3p16 = (_Float16*)alloc(2048*2);

    // Pack FIRST, as its own launch: consumers are in later launches only
    // (intra-launch block ordering is undefined -> round-6 race, fixed here).
    pack_kernel<<<1, 256, 0, stream>>>(
        fr_w1, pv_w1, fr_w2, fr_w3, pv_w2, pv_w3, fo_w1, fo_w2, fo_w3,
        aWr, aWs, aWp, frW2p, frW3p16, pvW2p, pvW3p16, foW1p, foW2p16, foW3p16);

    fused_pre_kernel<<<PREA_BLOCKS + A2_BLOCKS, 256, 0, stream>>>(
        x, y, fr_b1, pv_w1, pv_b1,
        (const half8*)aWr, (const half8*)aWs, (const half8*)aWp,
        frA, frB, pvA, pvV);

    edge_mfma_kernel<<<SENDER_BLOCKS + PV_BLOCKS, 256, 0, stream>>>(
        frA, frB, pvV, pvA,
        (const half8*)frW2p, (const half4v*)frW3p16,
        (const half8*)pvW2p, (const half4v*)pvW3p16,
        fr_b2, fr_b3, pv_b2, pv_b3, Epp, Epv2);

    prep_kernel<<<(BATCH*NPART*HP)/256, 256, 0, stream>>>(x, Epp, Epv2, cin);

    stageD_mfma_kernel<<<BATCH/4, 256, 0, stream>>>(cin,
        (const half8*)foW1p, (const half4v*)foW2p16, (const half4v*)foW3p16,
        fo_b1, fo_b2, fo_b3, fc_w, fc_b, out);
}